// Round 1
// 299.064 us; speedup vs baseline: 1.0262x; 1.0262x over previous
//
#include <hip/hip_runtime.h>
#include <cstdint>
#include <cstddef>

#define M_TOT 32768   // B*N
#define D_    256
#define DN_   128
#define TWO_D 512
#define H_    1024
#define TWO_H 2048

typedef unsigned short ushort_t;
typedef __attribute__((ext_vector_type(8))) short bf16x8;  // 8 bf16 = 4 VGPRs
typedef __attribute__((ext_vector_type(4))) float f32x4;

__device__ __forceinline__ ushort_t f2bf(float f) {
  union { float f; uint32_t i; } v; v.f = f;
  uint32_t r = v.i + 0x7fffu + ((v.i >> 16) & 1u);
  return (ushort_t)(r >> 16);
}

__device__ __forceinline__ void async_ld16(const void* g, void* l) {
  __builtin_amdgcn_global_load_lds(
      (const __attribute__((address_space(1))) void*)g,
      (__attribute__((address_space(3))) void*)l, 16, 0, 0);
}

// ---------------- tiny cond GEMM: ss[b][j] = ctx[b]·cond_w[:,j] + cond_b[j]  (all f32)
__global__ __launch_bounds__(256) void cond_ss_kernel(
    const float* __restrict__ ctx, const float* __restrict__ cond_w,
    const float* __restrict__ cond_b, float* __restrict__ ss) {
  int j = blockIdx.x * 256 + threadIdx.x;   // 4096 total: b=j>>9, col=j&511
  int b = j >> 9, col = j & 511;
  float acc = cond_b[col];
  for (int k = 0; k < DN_; ++k)
    acc += ctx[b * DN_ + k] * cond_w[k * TWO_D + col];
  ss[j] = acc;
}

// ---------------- tiled transpose: f32 [R][C] -> bf16 [C][R]  (64x64 tiles)
__global__ __launch_bounds__(256) void transpose_f32_bf16_kernel(
    const float* __restrict__ in, ushort_t* __restrict__ out, int R, int C) {
  __shared__ float T[64 * 65];
  int ctiles = C >> 6;
  int bi = blockIdx.x / ctiles, bj = blockIdx.x % ctiles;
  int r0 = bi * 64, c0 = bj * 64;
  int tid = threadIdx.x;
#pragma unroll
  for (int it = 0; it < 16; ++it) {
    int idx = it * 256 + tid;            // 0..4095
    int r = idx >> 6, c = idx & 63;
    T[r * 65 + c] = in[(size_t)(r0 + r) * C + c0 + c];
  }
  __syncthreads();
#pragma unroll
  for (int it = 0; it < 8; ++it) {
    int idx = it * 256 + tid;            // 0..2047
    int a = idx >> 5;                    // in-col -> out row
    int b = (idx & 31) * 2;              // in-row pair -> out col pair
    uint32_t pk = (uint32_t)f2bf(T[b * 65 + a]) |
                  ((uint32_t)f2bf(T[(b + 1) * 65 + a]) << 16);
    *(uint32_t*)&out[(size_t)(c0 + a) * R + r0 + b] = pk;
  }
}

// ---------------- emb gather -> W2T[f*8+o][d] = emb[idx[f]][d*8+o], coalesced 16B writes
__global__ __launch_bounds__(256) void gather_emb_kernel(
    const float* __restrict__ emb, const int* __restrict__ idx,
    ushort_t* __restrict__ W2T) {
  int f = blockIdx.x;                    // 0..127
  // int64-vs-int32 sniff: if idx is int64 (<1024 values), odd words are 0
  bool looks64 = (idx[1] == 0) & (idx[3] == 0) & (idx[5] == 0) & (idx[7] == 0);
  int fi = looks64 ? idx[2 * f] : idx[f];
  const float* src = emb + (size_t)fi * 2048;
  int o = threadIdx.x >> 5, d0 = (threadIdx.x & 31) * 8;
  ushort_t buf[8];
#pragma unroll
  for (int k = 0; k < 8; ++k) buf[k] = f2bf(src[(d0 + k) * 8 + o]);
  *(bf16x8*)&W2T[(size_t)(f * 8 + o) * 256 + d0] = *(bf16x8*)buf;
}

// ---------------- fused LayerNorm + FiLM  (one wave per row of 256), f32 in -> bf16 out
__global__ __launch_bounds__(256) void ln_film_kernel(
    const float* __restrict__ x, const float* __restrict__ ss,
    ushort_t* __restrict__ h) {
  int row = blockIdx.x * 4 + (threadIdx.x >> 6);
  int lane = threadIdx.x & 63;
  int b = row >> 12;
  const float* xr = x + (size_t)row * D_;
  float4 pk = *(const float4*)(xr + lane * 4);
  float f0 = pk.x, f1 = pk.y, f2 = pk.z, f3 = pk.w;
  float s = f0 + f1 + f2 + f3;
  float q = f0 * f0 + f1 * f1 + f2 * f2 + f3 * f3;
#pragma unroll
  for (int off = 32; off > 0; off >>= 1) {
    s += __shfl_xor(s, off, 64);
    q += __shfl_xor(q, off, 64);
  }
  float mean = s * (1.0f / 256.0f);
  float var = q * (1.0f / 256.0f) - mean * mean;
  float rs = rsqrtf(var + 1e-5f);
  int d = lane * 4;
  const float* ssb = ss + b * TWO_D;
  float o0 = (f0 - mean) * rs * (1.0f + ssb[d + 0]) + ssb[256 + d + 0];
  float o1 = (f1 - mean) * rs * (1.0f + ssb[d + 1]) + ssb[256 + d + 1];
  float o2 = (f2 - mean) * rs * (1.0f + ssb[d + 2]) + ssb[256 + d + 2];
  float o3 = (f3 - mean) * rs * (1.0f + ssb[d + 3]) + ssb[256 + d + 3];
  uint2 st;
  st.x = (uint32_t)f2bf(o0) | ((uint32_t)f2bf(o1) << 16);
  st.y = (uint32_t)f2bf(o2) | ((uint32_t)f2bf(o3) << 16);
  *(uint2*)(h + (size_t)row * D_ + lane * 4) = st;
}

// ---------------- fused gated-FFN: y = (gelu(h@Wu+bu)*(h@Wv+bv)) @ Wout + bout
// Pipelined 3-phase schedule per gate chunk j (ping-pong Sh, raw barriers,
// counted self-vmcnt; loads for phase k+1 issued right after barrier k):
//   A: compute in-proj s=0 from cur  | stage BuBv s=1 -> nxt
//   B: compute in-proj s=1 from cur  | stage Wout(j)  -> nxt
//   C: gelu->Gs + out-proj from cur  | stage BuBv(j+1,s=0) -> nxt
// h fragments live in registers per wave (a_reg[8]); no A-tile in LDS.
__global__ __launch_bounds__(256, 2) void ffn_fused_kernel(
    const ushort_t* __restrict__ h,      // [32768][256] bf16
    const ushort_t* __restrict__ WinT,   // [2048][256] bf16 (u rows 0..1023, v 1024..2047)
    const float* __restrict__ bin,       // [2048] f32
    const ushort_t* __restrict__ WoutT,  // [256][1024] bf16
    const float* __restrict__ bout,      // [256] f32
    ushort_t* __restrict__ y) {          // [32768][256] bf16
  __shared__ ushort_t Sh[2][16384];      // 2 x 32 KB ping-pong staging (32 tiles of 16x32)
  __shared__ ushort_t Gs[64 * 72];       // 9.2 KB: g chunk, row-major stride 72
  const int tid = threadIdx.x, lane = tid & 63, wave = tid >> 6;
  const int r = lane >> 2, q = lane & 3;         // staging lane decomposition
  const int l15 = lane & 15, l4 = lane >> 4;
  const int m0 = blockIdx.x * 64;
  const int fragoff = l15 * 32 + l4 * 8;         // element offset inside a 16x32 tile

  // hoisted per-thread staging base pointers (bytes)
  // BuBv tile for this wave: rows [j*64 + wave*16 + r], cols q*8 + (s*128 + i*32)
  const char* winp  = (const char*)WinT  + (wave * 16 + r) * 512 + q * 16;
  // Wout tile nt = wave+4i (s2 in {0,1}): rows [nt*16 + r], cols j*64 + s2*32 + q*8
  const char* woutp = (const char*)WoutT + (size_t)wave * 32768 + r * 2048 + q * 16;

  // A fragments (this wave's 16 h-rows) -> registers; issued before any staging
  const ushort_t* hp = h + (size_t)(m0 + wave * 16 + l15) * 256 + l4 * 8;
  bf16x8 a_reg[8];
#pragma unroll
  for (int kc = 0; kc < 8; ++kc) a_reg[kc] = *(const bf16x8*)(hp + kc * 32);

  // prologue: stage BuBv(j=0, s=0) -> Sh[0]
#pragma unroll
  for (int i = 0; i < 4; ++i) {
    int t = i * 4 + wave;
    async_ld16(winp + i * 64,          &Sh[0][t * 512]);
    async_ld16(winp + i * 64 + 524288, &Sh[0][(16 + t) * 512]);
  }

  f32x4 yac[16] = {};                    // y: 16 n-tiles of 16 cols
  int pb = 0;

  for (int j = 0; j < 16; ++j) {
    const int jb = j * 32768;            // byte offset of gate-chunk j in WinT
    f32x4 uac[4] = {}, vac[4] = {};

    // ---------- phase A: in-proj s=0 from Sh[pb]; stage BuBv s=1 -> Sh[pb^1]
    asm volatile("s_waitcnt vmcnt(0)" ::: "memory");
    __builtin_amdgcn_s_barrier();
    asm volatile("" ::: "memory");
    {
      ushort_t* nxt = Sh[pb ^ 1];
#pragma unroll
      for (int i = 0; i < 4; ++i) {
        int t = i * 4 + wave;
        async_ld16(winp + jb + 256 + i * 64,          &nxt[t * 512]);
        async_ld16(winp + jb + 256 + i * 64 + 524288, &nxt[(16 + t) * 512]);
      }
      const ushort_t* cur = Sh[pb];
      __builtin_amdgcn_s_setprio(1);
#pragma unroll
      for (int ks = 0; ks < 4; ++ks) {
        bf16x8 af = a_reg[ks];           // s = 0
#pragma unroll
        for (int jt = 0; jt < 4; ++jt) {
          bf16x8 bu = *(const bf16x8*)&cur[(ks * 4 + jt) * 512 + fragoff];
          bf16x8 bv = *(const bf16x8*)&cur[(16 + ks * 4 + jt) * 512 + fragoff];
          uac[jt] = __builtin_amdgcn_mfma_f32_16x16x32_bf16(af, bu, uac[jt], 0, 0, 0);
          vac[jt] = __builtin_amdgcn_mfma_f32_16x16x32_bf16(af, bv, vac[jt], 0, 0, 0);
        }
      }
      __builtin_amdgcn_s_setprio(0);
    }
    pb ^= 1;

    // ---------- phase B: in-proj s=1 from Sh[pb]; stage Wout(j) -> Sh[pb^1]
    asm volatile("s_waitcnt vmcnt(0)" ::: "memory");
    __builtin_amdgcn_s_barrier();
    asm volatile("" ::: "memory");
    {
      ushort_t* nxt = Sh[pb ^ 1];
#pragma unroll
      for (int i = 0; i < 4; ++i) {
        int t = i * 4 + wave;
        async_ld16(woutp + (size_t)i * 131072 + j * 128,      &nxt[t * 512]);
        async_ld16(woutp + (size_t)i * 131072 + j * 128 + 64, &nxt[(16 + t) * 512]);
      }
      const ushort_t* cur = Sh[pb];
      __builtin_amdgcn_s_setprio(1);
#pragma unroll
      for (int ks = 0; ks < 4; ++ks) {
        bf16x8 af = a_reg[4 + ks];       // s = 1
#pragma unroll
        for (int jt = 0; jt < 4; ++jt) {
          bf16x8 bu = *(const bf16x8*)&cur[(ks * 4 + jt) * 512 + fragoff];
          bf16x8 bv = *(const bf16x8*)&cur[(16 + ks * 4 + jt) * 512 + fragoff];
          uac[jt] = __builtin_amdgcn_mfma_f32_16x16x32_bf16(af, bu, uac[jt], 0, 0, 0);
          vac[jt] = __builtin_amdgcn_mfma_f32_16x16x32_bf16(af, bv, vac[jt], 0, 0, 0);
        }
      }
      __builtin_amdgcn_s_setprio(0);
    }
    pb ^= 1;

    // ---------- phase C: gelu->Gs, out-proj from Sh[pb]; stage BuBv(j+1,s=0) -> Sh[pb^1]
    asm volatile("s_waitcnt vmcnt(0)" ::: "memory");
    __builtin_amdgcn_s_barrier();
    asm volatile("" ::: "memory");
    if (j < 15) {
      ushort_t* nxt = Sh[pb ^ 1];
#pragma unroll
      for (int i = 0; i < 4; ++i) {
        int t = i * 4 + wave;
        async_ld16(winp + jb + 32768 + i * 64,          &nxt[t * 512]);
        async_ld16(winp + jb + 32768 + i * 64 + 524288, &nxt[(16 + t) * 512]);
      }
    }
    // gelu-gate -> Gs (own rows only; same-wave LDS dep, no barrier)
#pragma unroll
    for (int jt = 0; jt < 4; ++jt) {
      int col = jt * 16 + l15;
      float bub = bin[j * 64 + col];
      float bvb = bin[1024 + j * 64 + col];
#pragma unroll
      for (int rr = 0; rr < 4; ++rr) {
        float u = uac[jt][rr] + bub;
        float v = vac[jt][rr] + bvb;
        float t = 0.7978845608028654f * (u + 0.044715f * u * u * u);
        float e = __expf(2.0f * t);
        float th = 1.0f - 2.0f / (e + 1.0f);
        float gl = 0.5f * u * (1.0f + th);
        Gs[(wave * 16 + l4 * 4 + rr) * 72 + col] = f2bf(gl * v);
      }
    }
    {
      const ushort_t* cur = Sh[pb];
#pragma unroll
      for (int s2 = 0; s2 < 2; ++s2) {   // K=64 of G, two 32-subs
        bf16x8 gf = *(const bf16x8*)&Gs[(wave * 16 + l15) * 72 + s2 * 32 + l4 * 8];
        __builtin_amdgcn_s_setprio(1);
#pragma unroll
        for (int nt = 0; nt < 16; ++nt) {
          bf16x8 bw = *(const bf16x8*)&cur[(s2 * 16 + nt) * 512 + fragoff];
          yac[nt] = __builtin_amdgcn_mfma_f32_16x16x32_bf16(gf, bw, yac[nt], 0, 0, 0);
        }
        __builtin_amdgcn_s_setprio(0);
      }
    }
    pb ^= 1;
  }

  // epilogue: y + bout -> bf16 via Sh (stride 264), then vectorized 16B stores
  asm volatile("s_waitcnt vmcnt(0)" ::: "memory");
  __builtin_amdgcn_s_barrier();          // all waves done reading Sh
  asm volatile("" ::: "memory");
  ushort_t* E = &Sh[0][0];               // 64 x 264 spans both buffers (contiguous)
#pragma unroll
  for (int nt = 0; nt < 16; ++nt) {
    int col = nt * 16 + l15;
    float bb = bout[col];
#pragma unroll
    for (int rr = 0; rr < 4; ++rr)
      E[(wave * 16 + l4 * 4 + rr) * 264 + col] = f2bf(yac[nt][rr] + bb);
  }
  asm volatile("s_waitcnt lgkmcnt(0)" ::: "memory");
  __builtin_amdgcn_s_barrier();
  asm volatile("" ::: "memory");
#pragma unroll
  for (int it = 0; it < 8; ++it) {
    int id = it * 256 + tid;             // 0..2047: rr = row, cc = 8-col chunk
    int rr = id >> 5, cc = id & 31;
    bf16x8 vv = *(const bf16x8*)&E[rr * 264 + cc * 8];
    *(bf16x8*)&y[(size_t)(m0 + rr) * 256 + cc * 8] = vv;
  }
}

// ---------------- out GEMM: out[M][1024] = y[M][256] @ W2T[1024][256]^T, f32 out
// 128x128 tile, BK=64 (4 iters), 4 waves (2x2), LDS-roundtrip f32x4 epilogue.
__global__ __launch_bounds__(256, 2) void gemm_out_kernel(
    const ushort_t* __restrict__ A, const ushort_t* __restrict__ BT,
    float* __restrict__ C) {
  __shared__ ushort_t As[128 * 64];      // 16 tiles of 16x32: t = rt*2 + ks
  __shared__ ushort_t Bs[128 * 64];
  __shared__ float Cs[64 * 132];
  const int tid = threadIdx.x, lane = tid & 63, wave = tid >> 6;
  const int wm = wave >> 1, wn = wave & 1;
  const int m0 = blockIdx.x * 128, n0 = blockIdx.y * 128;
  const int r = lane >> 2, q = lane & 3;
  const int l15 = lane & 15, l4 = lane >> 4;
  const int fragoff = l15 * 32 + l4 * 8;
  const int N = 1024, K = 256;
  f32x4 acc[4][4] = {};
  for (int k0 = 0; k0 < K; k0 += 64) {
    for (int t = wave; t < 16; t += 4) {
      int rt = t >> 1, ks = t & 1;
      async_ld16(A + (size_t)(m0 + rt * 16 + r) * K + k0 + ks * 32 + q * 8, &As[t * 512]);
      async_ld16(BT + (size_t)(n0 + rt * 16 + r) * K + k0 + ks * 32 + q * 8, &Bs[t * 512]);
    }
    __syncthreads();
#pragma unroll
    for (int ks = 0; ks < 2; ++ks) {
      bf16x8 a[4], b[4];
#pragma unroll
      for (int i = 0; i < 4; ++i)
        a[i] = *(const bf16x8*)&As[((wm * 4 + i) * 2 + ks) * 512 + fragoff];
#pragma unroll
      for (int jt = 0; jt < 4; ++jt)
        b[jt] = *(const bf16x8*)&Bs[((wn * 4 + jt) * 2 + ks) * 512 + fragoff];
#pragma unroll
      for (int i = 0; i < 4; ++i)
#pragma unroll
        for (int jt = 0; jt < 4; ++jt)
          acc[i][jt] = __builtin_amdgcn_mfma_f32_16x16x32_bf16(a[i], b[jt], acc[i][jt], 0, 0, 0);
    }
    __syncthreads();
  }
#pragma unroll
  for (int p = 0; p < 2; ++p) {
    __syncthreads();
    if (wm == p) {
#pragma unroll
      for (int jt = 0; jt < 4; ++jt) {
        int col = wn * 64 + jt * 16 + l15;
#pragma unroll
        for (int i = 0; i < 4; ++i) {
          int rl = i * 16 + (l4 << 2);
#pragma unroll
          for (int rr = 0; rr < 4; ++rr)
            Cs[(rl + rr) * 132 + col] = acc[i][jt][rr];
        }
      }
    }
    __syncthreads();
#pragma unroll
    for (int it = 0; it < 8; ++it) {
      int t = it * 256 + tid;            // 0..2047
      int rr = t >> 5, c = (t & 31) * 4; // row 0..63, col 0..124
      float4 v = *(const float4*)&Cs[rr * 132 + c];
      *(float4*)&C[(size_t)(m0 + p * 64 + rr) * N + n0 + c] = v;
    }
  }
}

extern "C" void kernel_launch(void* const* d_in, const int* in_sizes, int n_in,
                              void* d_out, int out_size, void* d_ws, size_t ws_size,
                              hipStream_t stream) {
  const float* x      = (const float*)d_in[0];
  const float* ctx    = (const float*)d_in[1];
  const int*   idx    = (const int*)d_in[2];
  const float* cond_w = (const float*)d_in[3];
  const float* cond_b = (const float*)d_in[4];
  const float* w_in   = (const float*)d_in[5];
  const float* b_in   = (const float*)d_in[6];
  const float* w_out  = (const float*)d_in[7];
  const float* b_out  = (const float*)d_in[8];
  const float* emb    = (const float*)d_in[9];

  char* w = (char*)d_ws;
  float* ss = (float*)w;           w += (size_t)8 * TWO_D * 4;        // 16 KB
  ushort_t* h = (ushort_t*)w;      w += (size_t)M_TOT * D_ * 2;       // 16.8 MB
  ushort_t* y = (ushort_t*)w;      w += (size_t)M_TOT * D_ * 2;       // 16.8 MB
  ushort_t* WinT = (ushort_t*)w;   w += (size_t)TWO_H * D_ * 2;       // 1 MB
  ushort_t* WoutT = (ushort_t*)w;  w += (size_t)D_ * H_ * 2;          // 0.5 MB
  ushort_t* W2T = (ushort_t*)w;    w += (size_t)H_ * D_ * 2;          // 0.5 MB

  cond_ss_kernel<<<16, 256, 0, stream>>>(ctx, cond_w, cond_b, ss);
  transpose_f32_bf16_kernel<<<(D_ / 64) * (TWO_H / 64), 256, 0, stream>>>(w_in, WinT, D_, TWO_H);
  transpose_f32_bf16_kernel<<<(H_ / 64) * (D_ / 64), 256, 0, stream>>>(w_out, WoutT, H_, D_);
  gather_emb_kernel<<<128, 256, 0, stream>>>(emb, idx, W2T);
  ln_film_kernel<<<M_TOT / 4, 256, 0, stream>>>(x, ss, h);
  ffn_fused_kernel<<<M_TOT / 64, 256, 0, stream>>>(h, WinT, b_in, WoutT, b_out, y);
  gemm_out_kernel<<<dim3(M_TOT / 128, H_ / 128), 256, 0, stream>>>(y, W2T, (float*)d_out);
}

// Round 2
// 288.746 us; speedup vs baseline: 1.0629x; 1.0357x over previous
//
#include <hip/hip_runtime.h>
#include <cstdint>
#include <cstddef>

#define M_TOT 32768   // B*N
#define D_    256
#define DN_   128
#define TWO_D 512
#define H_    1024
#define TWO_H 2048

typedef unsigned short ushort_t;
typedef __attribute__((ext_vector_type(8))) short bf16x8;  // 8 bf16 = 4 VGPRs
typedef __attribute__((ext_vector_type(4))) float f32x4;

__device__ __forceinline__ ushort_t f2bf(float f) {
  union { float f; uint32_t i; } v; v.f = f;
  uint32_t r = v.i + 0x7fffu + ((v.i >> 16) & 1u);
  return (ushort_t)(r >> 16);
}

__device__ __forceinline__ void async_ld16(const void* g, void* l) {
  __builtin_amdgcn_global_load_lds(
      (const __attribute__((address_space(1))) void*)g,
      (__attribute__((address_space(3))) void*)l, 16, 0, 0);
}

// ---------------- tiny cond GEMM: ss[b][j] = ctx[b]·cond_w[:,j] + cond_b[j]  (all f32)
__global__ __launch_bounds__(256) void cond_ss_kernel(
    const float* __restrict__ ctx, const float* __restrict__ cond_w,
    const float* __restrict__ cond_b, float* __restrict__ ss) {
  int j = blockIdx.x * 256 + threadIdx.x;   // 4096 total: b=j>>9, col=j&511
  int b = j >> 9, col = j & 511;
  float acc = cond_b[col];
  for (int k = 0; k < DN_; ++k)
    acc += ctx[b * DN_ + k] * cond_w[k * TWO_D + col];
  ss[j] = acc;
}

// ---------------- tiled transpose: f32 [R][C] -> bf16 [C][R]  (64x64 tiles)
__global__ __launch_bounds__(256) void transpose_f32_bf16_kernel(
    const float* __restrict__ in, ushort_t* __restrict__ out, int R, int C) {
  __shared__ float T[64 * 65];
  int ctiles = C >> 6;
  int bi = blockIdx.x / ctiles, bj = blockIdx.x % ctiles;
  int r0 = bi * 64, c0 = bj * 64;
  int tid = threadIdx.x;
#pragma unroll
  for (int it = 0; it < 16; ++it) {
    int idx = it * 256 + tid;            // 0..4095
    int r = idx >> 6, c = idx & 63;
    T[r * 65 + c] = in[(size_t)(r0 + r) * C + c0 + c];
  }
  __syncthreads();
#pragma unroll
  for (int it = 0; it < 8; ++it) {
    int idx = it * 256 + tid;            // 0..2047
    int a = idx >> 5;                    // in-col -> out row
    int b = (idx & 31) * 2;              // in-row pair -> out col pair
    uint32_t pk = (uint32_t)f2bf(T[b * 65 + a]) |
                  ((uint32_t)f2bf(T[(b + 1) * 65 + a]) << 16);
    *(uint32_t*)&out[(size_t)(c0 + a) * R + r0 + b] = pk;
  }
}

// ---------------- emb gather -> W2T[f*8+o][d] = emb[idx[f]][d*8+o], coalesced 16B writes
__global__ __launch_bounds__(256) void gather_emb_kernel(
    const float* __restrict__ emb, const int* __restrict__ idx,
    ushort_t* __restrict__ W2T) {
  int f = blockIdx.x;                    // 0..127
  // int64-vs-int32 sniff: if idx is int64 (<1024 values), odd words are 0
  bool looks64 = (idx[1] == 0) & (idx[3] == 0) & (idx[5] == 0) & (idx[7] == 0);
  int fi = looks64 ? idx[2 * f] : idx[f];
  const float* src = emb + (size_t)fi * 2048;
  int o = threadIdx.x >> 5, d0 = (threadIdx.x & 31) * 8;
  ushort_t buf[8];
#pragma unroll
  for (int k = 0; k < 8; ++k) buf[k] = f2bf(src[(d0 + k) * 8 + o]);
  *(bf16x8*)&W2T[(size_t)(f * 8 + o) * 256 + d0] = *(bf16x8*)buf;
}

// ---------------- fused LayerNorm + FiLM  (one wave per row of 256), f32 in -> bf16 out
__global__ __launch_bounds__(256) void ln_film_kernel(
    const float* __restrict__ x, const float* __restrict__ ss,
    ushort_t* __restrict__ h) {
  int row = blockIdx.x * 4 + (threadIdx.x >> 6);
  int lane = threadIdx.x & 63;
  int b = row >> 12;
  const float* xr = x + (size_t)row * D_;
  float4 pk = *(const float4*)(xr + lane * 4);
  float f0 = pk.x, f1 = pk.y, f2 = pk.z, f3 = pk.w;
  float s = f0 + f1 + f2 + f3;
  float q = f0 * f0 + f1 * f1 + f2 * f2 + f3 * f3;
#pragma unroll
  for (int off = 32; off > 0; off >>= 1) {
    s += __shfl_xor(s, off, 64);
    q += __shfl_xor(q, off, 64);
  }
  float mean = s * (1.0f / 256.0f);
  float var = q * (1.0f / 256.0f) - mean * mean;
  float rs = rsqrtf(var + 1e-5f);
  int d = lane * 4;
  const float* ssb = ss + b * TWO_D;
  float o0 = (f0 - mean) * rs * (1.0f + ssb[d + 0]) + ssb[256 + d + 0];
  float o1 = (f1 - mean) * rs * (1.0f + ssb[d + 1]) + ssb[256 + d + 1];
  float o2 = (f2 - mean) * rs * (1.0f + ssb[d + 2]) + ssb[256 + d + 2];
  float o3 = (f3 - mean) * rs * (1.0f + ssb[d + 3]) + ssb[256 + d + 3];
  uint2 st;
  st.x = (uint32_t)f2bf(o0) | ((uint32_t)f2bf(o1) << 16);
  st.y = (uint32_t)f2bf(o2) | ((uint32_t)f2bf(o3) << 16);
  *(uint2*)(h + (size_t)row * D_ + lane * 4) = st;
}

// ---------------- fused gated-FFN: y = (gelu(h@Wu+bu)*(h@Wv+bv)) @ Wout + bout
// 2x2 wave grid: wave (wm,wn) owns rows [wm*32, wm*32+32) x N-half wn.
// A (h rows) fully register-resident (16x bf16x8) -> every B-frag LDS read
// feeds 2 MFMAs (was 1). Tiles XOR-swizzled (l4 ^= (l15>>1)&3 on read,
// q ^= (r>>1)&3 on staging source) to kill the 8-way ds_read_b128 bank
// conflict of linear 16x32 tiles. 3-phase ping-pong per gate chunk j:
//   A: u,v MFMA for K 0..127   | stage BuBv K 128..255 -> nxt
//   B: u,v MFMA for K 128..255 | stage Wout(j) -> nxt
//   C: gelu->Gs, [barrier], out-proj | stage BuBv(j+1, K 0..127) -> nxt
__global__ __launch_bounds__(256, 2) void ffn_fused_kernel(
    const ushort_t* __restrict__ h,      // [32768][256] bf16
    const ushort_t* __restrict__ WinT,   // [2048][256] bf16 (u rows 0..1023, v 1024..2047)
    const float* __restrict__ bin,       // [2048] f32
    const ushort_t* __restrict__ WoutT,  // [256][1024] bf16
    const float* __restrict__ bout,      // [256] f32
    ushort_t* __restrict__ y) {          // [32768][256] bf16
  __shared__ ushort_t Sh[2][16384];      // 2 x 32 KB ping-pong staging (32 tiles of 16x32)
  __shared__ ushort_t Gs[64 * 72];       // 9.2 KB: g chunk, row-major stride 72
  const int tid = threadIdx.x, lane = tid & 63, wave = tid >> 6;
  const int wm = wave >> 1, wn = wave & 1;
  const int r = lane >> 2, q = lane & 3;         // staging lane decomposition
  const int qs = q ^ ((r >> 1) & 3);             // swizzled source col-chunk
  const int l15 = lane & 15, l4 = lane >> 4;
  const int m0 = blockIdx.x * 64;
  // swizzled fragment offset inside a 16x32 tile (ushort units)
  const int fragoff = l15 * 32 + (l4 ^ ((l15 >> 1) & 3)) * 8;

  // hoisted per-thread staging base pointers (bytes)
  const char* winp  = (const char*)WinT  + (wave * 16 + r) * 512 + qs * 16;
  const char* woutp = (const char*)WoutT + (size_t)wave * 32768 + r * 2048 + qs * 16;

  // A fragments: this wave's 32 h-rows, all K=256, in registers (64 VGPR)
  const ushort_t* hp = h + (size_t)(m0 + wm * 32 + l15) * 256 + l4 * 8;
  bf16x8 a_reg[2][8];
#pragma unroll
  for (int rt = 0; rt < 2; ++rt)
#pragma unroll
    for (int kc = 0; kc < 8; ++kc)
      a_reg[rt][kc] = *(const bf16x8*)(hp + rt * 4096 + kc * 32);

  // prologue: stage BuBv(j=0, s=0) -> Sh[0]
#pragma unroll
  for (int i = 0; i < 4; ++i) {
    int t = i * 4 + wave;
    async_ld16(winp + i * 64,          &Sh[0][t * 512]);
    async_ld16(winp + i * 64 + 524288, &Sh[0][(16 + t) * 512]);
  }

  f32x4 yac[2][8] = {};                  // rows rt*16, out-cols wn*128 + nt8*16
  int pb = 0;

  for (int j = 0; j < 16; ++j) {
    const int jb = j * 32768;            // byte offset of gate-chunk j in WinT
    f32x4 uac[2][2] = {}, vac[2][2] = {};

    // ---------- phase A: in-proj K 0..127 from Sh[pb]; stage BuBv s=1 -> Sh[pb^1]
    asm volatile("s_waitcnt vmcnt(0)" ::: "memory");
    __builtin_amdgcn_s_barrier();
    asm volatile("" ::: "memory");
    {
      ushort_t* nxt = Sh[pb ^ 1];
#pragma unroll
      for (int i = 0; i < 4; ++i) {
        int t = i * 4 + wave;
        async_ld16(winp + jb + 256 + i * 64,          &nxt[t * 512]);
        async_ld16(winp + jb + 256 + i * 64 + 524288, &nxt[(16 + t) * 512]);
      }
      const ushort_t* cur = Sh[pb];
      __builtin_amdgcn_s_setprio(1);
#pragma unroll
      for (int ks = 0; ks < 4; ++ks) {
#pragma unroll
        for (int jj = 0; jj < 2; ++jj) {
          int t = ks * 4 + wn * 2 + jj;
          bf16x8 bu = *(const bf16x8*)&cur[t * 512 + fragoff];
          bf16x8 bv = *(const bf16x8*)&cur[(16 + t) * 512 + fragoff];
          uac[0][jj] = __builtin_amdgcn_mfma_f32_16x16x32_bf16(a_reg[0][ks], bu, uac[0][jj], 0, 0, 0);
          uac[1][jj] = __builtin_amdgcn_mfma_f32_16x16x32_bf16(a_reg[1][ks], bu, uac[1][jj], 0, 0, 0);
          vac[0][jj] = __builtin_amdgcn_mfma_f32_16x16x32_bf16(a_reg[0][ks], bv, vac[0][jj], 0, 0, 0);
          vac[1][jj] = __builtin_amdgcn_mfma_f32_16x16x32_bf16(a_reg[1][ks], bv, vac[1][jj], 0, 0, 0);
        }
      }
      __builtin_amdgcn_s_setprio(0);
    }
    pb ^= 1;

    // ---------- phase B: in-proj K 128..255 from Sh[pb]; stage Wout(j) -> Sh[pb^1]
    asm volatile("s_waitcnt vmcnt(0)" ::: "memory");
    __builtin_amdgcn_s_barrier();
    asm volatile("" ::: "memory");
    {
      ushort_t* nxt = Sh[pb ^ 1];
#pragma unroll
      for (int i = 0; i < 4; ++i) {
        int t = i * 4 + wave;
        async_ld16(woutp + (size_t)i * 131072 + j * 128,      &nxt[t * 512]);
        async_ld16(woutp + (size_t)i * 131072 + j * 128 + 64, &nxt[(16 + t) * 512]);
      }
      const ushort_t* cur = Sh[pb];
      __builtin_amdgcn_s_setprio(1);
#pragma unroll
      for (int ks = 0; ks < 4; ++ks) {
#pragma unroll
        for (int jj = 0; jj < 2; ++jj) {
          int t = ks * 4 + wn * 2 + jj;
          bf16x8 bu = *(const bf16x8*)&cur[t * 512 + fragoff];
          bf16x8 bv = *(const bf16x8*)&cur[(16 + t) * 512 + fragoff];
          uac[0][jj] = __builtin_amdgcn_mfma_f32_16x16x32_bf16(a_reg[0][4 + ks], bu, uac[0][jj], 0, 0, 0);
          uac[1][jj] = __builtin_amdgcn_mfma_f32_16x16x32_bf16(a_reg[1][4 + ks], bu, uac[1][jj], 0, 0, 0);
          vac[0][jj] = __builtin_amdgcn_mfma_f32_16x16x32_bf16(a_reg[0][4 + ks], bv, vac[0][jj], 0, 0, 0);
          vac[1][jj] = __builtin_amdgcn_mfma_f32_16x16x32_bf16(a_reg[1][4 + ks], bv, vac[1][jj], 0, 0, 0);
        }
      }
      __builtin_amdgcn_s_setprio(0);
    }
    pb ^= 1;

    // ---------- phase C: gelu->Gs, [Gs barrier], out-proj from Sh[pb];
    //            stage BuBv(j+1,s=0) -> Sh[pb^1]
    asm volatile("s_waitcnt vmcnt(0)" ::: "memory");
    __builtin_amdgcn_s_barrier();
    asm volatile("" ::: "memory");
    if (j < 15) {
      ushort_t* nxt = Sh[pb ^ 1];
#pragma unroll
      for (int i = 0; i < 4; ++i) {
        int t = i * 4 + wave;
        async_ld16(winp + jb + 32768 + i * 64,          &nxt[t * 512]);
        async_ld16(winp + jb + 32768 + i * 64 + 524288, &nxt[(16 + t) * 512]);
      }
    }
    // gelu-gate -> Gs (this wave's 32 rows x 32 gate-cols)
#pragma unroll
    for (int jj = 0; jj < 2; ++jj) {
      int gcol = wn * 32 + jj * 16 + l15;
      float bub = bin[j * 64 + gcol];
      float bvb = bin[1024 + j * 64 + gcol];
#pragma unroll
      for (int rt = 0; rt < 2; ++rt) {
#pragma unroll
        for (int rr = 0; rr < 4; ++rr) {
          float u = uac[rt][jj][rr] + bub;
          float v = vac[rt][jj][rr] + bvb;
          float t = 0.7978845608028654f * (u + 0.044715f * u * u * u);
          float e = __expf(2.0f * t);
          float th = 1.0f - 2.0f / (e + 1.0f);
          float gl = 0.5f * u * (1.0f + th);
          Gs[(wm * 32 + rt * 16 + l4 * 4 + rr) * 72 + gcol] = f2bf(gl * v);
        }
      }
    }
    asm volatile("s_waitcnt lgkmcnt(0)" ::: "memory");
    __builtin_amdgcn_s_barrier();        // G shared across the wn-pair
    asm volatile("" ::: "memory");
    {
      const ushort_t* cur = Sh[pb];
#pragma unroll
      for (int s2 = 0; s2 < 2; ++s2) {
        bf16x8 gf0 = *(const bf16x8*)&Gs[(wm * 32 + l15) * 72 + s2 * 32 + l4 * 8];
        bf16x8 gf1 = *(const bf16x8*)&Gs[(wm * 32 + 16 + l15) * 72 + s2 * 32 + l4 * 8];
        __builtin_amdgcn_s_setprio(1);
#pragma unroll
        for (int nt8 = 0; nt8 < 8; ++nt8) {
          int t = s2 * 16 + wn * 8 + nt8;
          bf16x8 bw = *(const bf16x8*)&cur[t * 512 + fragoff];
          yac[0][nt8] = __builtin_amdgcn_mfma_f32_16x16x32_bf16(gf0, bw, yac[0][nt8], 0, 0, 0);
          yac[1][nt8] = __builtin_amdgcn_mfma_f32_16x16x32_bf16(gf1, bw, yac[1][nt8], 0, 0, 0);
        }
        __builtin_amdgcn_s_setprio(0);
      }
    }
    pb ^= 1;
  }

  // epilogue: y + bout -> bf16 via Sh (stride 264), then vectorized 16B stores
  asm volatile("s_waitcnt vmcnt(0)" ::: "memory");
  __builtin_amdgcn_s_barrier();          // all waves done reading Sh
  asm volatile("" ::: "memory");
  ushort_t* E = &Sh[0][0];               // 64 x 264 spans both buffers (contiguous)
#pragma unroll
  for (int nt8 = 0; nt8 < 8; ++nt8) {
    int col = wn * 128 + nt8 * 16 + l15;
    float bb = bout[col];
#pragma unroll
    for (int rt = 0; rt < 2; ++rt) {
#pragma unroll
      for (int rr = 0; rr < 4; ++rr)
        E[(wm * 32 + rt * 16 + l4 * 4 + rr) * 264 + col] = f2bf(yac[rt][nt8][rr] + bb);
    }
  }
  asm volatile("s_waitcnt lgkmcnt(0)" ::: "memory");
  __builtin_amdgcn_s_barrier();
  asm volatile("" ::: "memory");
#pragma unroll
  for (int it = 0; it < 8; ++it) {
    int id = it * 256 + tid;             // 0..2047: rr = row, cc = 8-col chunk
    int rr = id >> 5, cc = id & 31;
    bf16x8 vv = *(const bf16x8*)&E[rr * 264 + cc * 8];
    *(bf16x8*)&y[(size_t)(m0 + rr) * 256 + cc * 8] = vv;
  }
}

// ---------------- out GEMM: out[M][1024] = y[M][256] @ W2T[1024][256]^T, f32 out
// 128x128 tile, BK=64 (4 iters), 4 waves (2x2), swizzled tiles,
// LDS-roundtrip f32x4 epilogue.
__global__ __launch_bounds__(256, 2) void gemm_out_kernel(
    const ushort_t* __restrict__ A, const ushort_t* __restrict__ BT,
    float* __restrict__ C) {
  __shared__ ushort_t As[128 * 64];      // 16 tiles of 16x32: t = rt*2 + ks
  __shared__ ushort_t Bs[128 * 64];
  __shared__ float Cs[64 * 132];
  const int tid = threadIdx.x, lane = tid & 63, wave = tid >> 6;
  const int wm = wave >> 1, wn = wave & 1;
  const int m0 = blockIdx.x * 128, n0 = blockIdx.y * 128;
  const int r = lane >> 2, q = lane & 3;
  const int qs = q ^ ((r >> 1) & 3);     // swizzled source col-chunk
  const int l15 = lane & 15, l4 = lane >> 4;
  const int fragoff = l15 * 32 + (l4 ^ ((l15 >> 1) & 3)) * 8;
  const int N = 1024, K = 256;
  f32x4 acc[4][4] = {};
  for (int k0 = 0; k0 < K; k0 += 64) {
    for (int t = wave; t < 16; t += 4) {
      int rt = t >> 1, ks = t & 1;
      async_ld16(A + (size_t)(m0 + rt * 16 + r) * K + k0 + ks * 32 + qs * 8, &As[t * 512]);
      async_ld16(BT + (size_t)(n0 + rt * 16 + r) * K + k0 + ks * 32 + qs * 8, &Bs[t * 512]);
    }
    __syncthreads();
#pragma unroll
    for (int ks = 0; ks < 2; ++ks) {
      bf16x8 a[4], b[4];
#pragma unroll
      for (int i = 0; i < 4; ++i)
        a[i] = *(const bf16x8*)&As[((wm * 4 + i) * 2 + ks) * 512 + fragoff];
#pragma unroll
      for (int jt = 0; jt < 4; ++jt)
        b[jt] = *(const bf16x8*)&Bs[((wn * 4 + jt) * 2 + ks) * 512 + fragoff];
#pragma unroll
      for (int i = 0; i < 4; ++i)
#pragma unroll
        for (int jt = 0; jt < 4; ++jt)
          acc[i][jt] = __builtin_amdgcn_mfma_f32_16x16x32_bf16(a[i], b[jt], acc[i][jt], 0, 0, 0);
    }
    __syncthreads();
  }
#pragma unroll
  for (int p = 0; p < 2; ++p) {
    __syncthreads();
    if (wm == p) {
#pragma unroll
      for (int jt = 0; jt < 4; ++jt) {
        int col = wn * 64 + jt * 16 + l15;
#pragma unroll
        for (int i = 0; i < 4; ++i) {
          int rl = i * 16 + (l4 << 2);
#pragma unroll
          for (int rr = 0; rr < 4; ++rr)
            Cs[(rl + rr) * 132 + col] = acc[i][jt][rr];
        }
      }
    }
    __syncthreads();
#pragma unroll
    for (int it = 0; it < 8; ++it) {
      int t = it * 256 + tid;            // 0..2047
      int rr = t >> 5, c = (t & 31) * 4; // row 0..63, col 0..124
      float4 v = *(const float4*)&Cs[rr * 132 + c];
      *(float4*)&C[(size_t)(m0 + p * 64 + rr) * N + n0 + c] = v;
    }
  }
}

extern "C" void kernel_launch(void* const* d_in, const int* in_sizes, int n_in,
                              void* d_out, int out_size, void* d_ws, size_t ws_size,
                              hipStream_t stream) {
  const float* x      = (const float*)d_in[0];
  const float* ctx    = (const float*)d_in[1];
  const int*   idx    = (const int*)d_in[2];
  const float* cond_w = (const float*)d_in[3];
  const float* cond_b = (const float*)d_in[4];
  const float* w_in   = (const float*)d_in[5];
  const float* b_in   = (const float*)d_in[6];
  const float* w_out  = (const float*)d_in[7];
  const float* b_out  = (const float*)d_in[8];
  const float* emb    = (const float*)d_in[9];

  char* w = (char*)d_ws;
  float* ss = (float*)w;           w += (size_t)8 * TWO_D * 4;        // 16 KB
  ushort_t* h = (ushort_t*)w;      w += (size_t)M_TOT * D_ * 2;       // 16.8 MB
  ushort_t* y = (ushort_t*)w;      w += (size_t)M_TOT * D_ * 2;       // 16.8 MB
  ushort_t* WinT = (ushort_t*)w;   w += (size_t)TWO_H * D_ * 2;       // 1 MB
  ushort_t* WoutT = (ushort_t*)w;  w += (size_t)D_ * H_ * 2;          // 0.5 MB
  ushort_t* W2T = (ushort_t*)w;    w += (size_t)H_ * D_ * 2;          // 0.5 MB

  cond_ss_kernel<<<16, 256, 0, stream>>>(ctx, cond_w, cond_b, ss);
  transpose_f32_bf16_kernel<<<(D_ / 64) * (TWO_H / 64), 256, 0, stream>>>(w_in, WinT, D_, TWO_H);
  transpose_f32_bf16_kernel<<<(H_ / 64) * (D_ / 64), 256, 0, stream>>>(w_out, WoutT, H_, D_);
  gather_emb_kernel<<<128, 256, 0, stream>>>(emb, idx, W2T);
  ln_film_kernel<<<M_TOT / 4, 256, 0, stream>>>(x, ss, h);
  ffn_fused_kernel<<<M_TOT / 64, 256, 0, stream>>>(h, WinT, b_in, WoutT, b_out, y);
  gemm_out_kernel<<<dim3(M_TOT / 128, H_ / 128), 256, 0, stream>>>(y, W2T, (float*)d_out);
}